// Round 9
// baseline (367.397 us; speedup 1.0000x reference)
//
#include <hip/hip_runtime.h>

#define NN 50000
#define E0 200000
#define E2 400000
#define NGROUPS ((NN + 7) / 8)      // 6250
#define NCHUNK  ((NN + 255) / 256)  // 196
#define NTILES  ((NN + 63) / 64)    // 782

typedef __attribute__((ext_vector_type(8))) short short8;
typedef __attribute__((ext_vector_type(4))) float f32x4;

__device__ __forceinline__ float eluf(float x) { return x > 0.0f ? x : expm1f(x); }
__device__ __forceinline__ float sigmoidf(float x) { return 1.0f / (1.0f + expf(-x)); }
__device__ __forceinline__ unsigned rne_bf16(float x) {
    unsigned u = __float_as_uint(x);
    return (u + 0x7fffu + ((u >> 16) & 1u)) >> 16;
}

// ---------------- setup: weight split + spectral norm + zero cnt/fill/deg (1 dispatch)
__global__ __launch_bounds__(256) void k_setup(const float* __restrict__ W1, const float* __restrict__ W2,
                                               const float* __restrict__ Wl_in, const float* __restrict__ Wr_in,
                                               float* __restrict__ Wl_out, float* __restrict__ Wr_out,
                                               unsigned short* __restrict__ w1hi, unsigned short* __restrict__ w1lo,
                                               unsigned short* __restrict__ w2hi, unsigned short* __restrict__ w2lo,
                                               int* __restrict__ cnt, int* __restrict__ fill,
                                               float* __restrict__ deg) {
    __shared__ float W[32 * 33];
    __shared__ float us[32], vs[32], tmp[32];
    __shared__ float scal;
    int t = threadIdx.x;
    if (blockIdx.x < 2) {
        int l = blockIdx.x;
        for (int i = t; i < 1024; i += 256) W[(i >> 5) * 33 + (i & 31)] = Wr_in[l * 1024 + i];
        if (t < 32) us[t] = 0.17677669529663688f;
        __syncthreads();
        for (int it = 0; it < 20; ++it) {
            if (t < 32) { float a = 0; for (int r = 0; r < 32; ++r) a = fmaf(W[r * 33 + t], us[r], a); tmp[t] = a; }
            __syncthreads();
            if (t == 0) { float s = 0; for (int c = 0; c < 32; ++c) s += tmp[c] * tmp[c]; scal = 1.0f / (sqrtf(s) + 1e-12f); }
            __syncthreads();
            if (t < 32) vs[t] = tmp[t] * scal;
            __syncthreads();
            if (t < 32) { float a = 0; for (int c = 0; c < 32; ++c) a = fmaf(W[t * 33 + c], vs[c], a); tmp[t] = a; }
            __syncthreads();
            if (t == 0) { float s = 0; for (int r = 0; r < 32; ++r) s += tmp[r] * tmp[r]; scal = 1.0f / (sqrtf(s) + 1e-12f); }
            __syncthreads();
            if (t < 32) us[t] = tmp[t] * scal;
            __syncthreads();
        }
        if (t < 32) { float a = 0; for (int r = 0; r < 32; ++r) a = fmaf(W[r * 33 + t], us[r], a); tmp[t] = a; }
        __syncthreads();
        if (t == 0) {
            float s = 0; for (int c = 0; c < 32; ++c) s += tmp[c] * tmp[c];
            scal = (sqrtf(s) + 1e-12f) / s;   // 1/sigma
        }
        __syncthreads();
        for (int i = t; i < 1024; i += 256) Wr_out[l * 1024 + i] = W[(i >> 5) * 33 + (i & 31)] * scal;
        if (t == 0) {
            float M[9];
            for (int i = 0; i < 9; ++i) M[i] = Wl_in[l * 9 + i];
            float u[3] = {0.5773502691896258f, 0.5773502691896258f, 0.5773502691896258f};
            float v[3], u2[3];
            for (int it = 0; it < 20; ++it) {
                float s = 0;
                for (int c = 0; c < 3; ++c) { v[c] = M[c] * u[0] + M[3 + c] * u[1] + M[6 + c] * u[2]; s += v[c] * v[c]; }
                float inv = 1.0f / (sqrtf(s) + 1e-12f);
                for (int c = 0; c < 3; ++c) v[c] *= inv;
                s = 0;
                for (int r = 0; r < 3; ++r) { u2[r] = M[r * 3] * v[0] + M[r * 3 + 1] * v[1] + M[r * 3 + 2] * v[2]; s += u2[r] * u2[r]; }
                inv = 1.0f / (sqrtf(s) + 1e-12f);
                for (int r = 0; r < 3; ++r) u[r] = u2[r] * inv;
            }
            float s = 0;
            for (int c = 0; c < 3; ++c) { v[c] = M[c] * u[0] + M[3 + c] * u[1] + M[6 + c] * u[2]; s += v[c] * v[c]; }
            float inv = (sqrtf(s) + 1e-12f) / s;
            for (int i = 0; i < 9; ++i) Wl_out[l * 9 + i] = M[i] * inv;
        }
    } else {
        int base = (blockIdx.x - 2) * 256 + t;
        int stride = (gridDim.x - 2) * 256;
        for (int i = base; i < 96 * 128; i += stride) {
            float v = W1[i];
            unsigned h = rne_bf16(v);
            w1hi[i] = (unsigned short)h;
            w1lo[i] = (unsigned short)rne_bf16(v - __uint_as_float(h << 16));
        }
        for (int i = base; i < 32 * 96; i += stride) {
            float v = W2[i];
            unsigned h = rne_bf16(v);
            w2hi[i] = (unsigned short)h;
            w2lo[i] = (unsigned short)rne_bf16(v - __uint_as_float(h << 16));
        }
        for (int i = base; i < NN; i += stride) { cnt[i] = 0; fill[i] = 0; deg[i] = 0.0f; }
    }
}

// ---------------- MFMA GEMM, register-direct B (no LDS, no barriers):
// out[M,N] = act(X[M,K] @ W[N,K]^T + b), split-bf16 (3 MFMA products).
// B fragment loads are per-wave coalesced dwordx4 from L2-resident w{hi,lo}.
template<int K, int N, bool ELU, bool HIST>
__global__ __launch_bounds__(256) void k_gemm(const float* __restrict__ X,
                                              const unsigned short* __restrict__ Whi,
                                              const unsigned short* __restrict__ Wlo,
                                              const float* __restrict__ bias,
                                              float* __restrict__ out,
                                              const int* __restrict__ row, int* __restrict__ cnt) {
    constexpr int NT = N / 16;
    constexpr int KS = K / 32;
    int tid = threadIdx.x;
    int wave = tid >> 6, lane = tid & 63;
    int quad = lane >> 4, r16 = lane & 15;
    long m = (long)blockIdx.x * 64 + wave * 16 + r16;
    long mc = m < NN ? m : (NN - 1);      // clamp OOB A-loads; stores guarded
    const float* xrow = X + mc * K + quad * 8;
    short8 ah[KS], al[KS];
#pragma unroll
    for (int ks = 0; ks < KS; ++ks) {
        const float4* xp = (const float4*)(xrow + ks * 32);
        float4 p0 = xp[0], p1 = xp[1];
        float xv[8] = {p0.x, p0.y, p0.z, p0.w, p1.x, p1.y, p1.z, p1.w};
#pragma unroll
        for (int j = 0; j < 8; ++j) {
            unsigned h = rne_bf16(xv[j]);
            ah[ks][j] = (short)h;
            al[ks][j] = (short)rne_bf16(xv[j] - __uint_as_float(h << 16));
        }
    }
    f32x4 acc[NT];
#pragma unroll
    for (int t = 0; t < NT; ++t) acc[t] = (f32x4){0.f, 0.f, 0.f, 0.f};
#pragma unroll
    for (int t = 0; t < NT; ++t) {
        int bo = (t * 16 + r16) * K + quad * 8;
#pragma unroll
        for (int ks = 0; ks < KS; ++ks) {
            short8 bh = *(const short8*)&Whi[bo + ks * 32];
            short8 bl = *(const short8*)&Wlo[bo + ks * 32];
            acc[t] = __builtin_amdgcn_mfma_f32_16x16x32_bf16(ah[ks], bh, acc[t], 0, 0, 0);
            acc[t] = __builtin_amdgcn_mfma_f32_16x16x32_bf16(al[ks], bh, acc[t], 0, 0, 0);
            acc[t] = __builtin_amdgcn_mfma_f32_16x16x32_bf16(ah[ks], bl, acc[t], 0, 0, 0);
        }
    }
    // C/D layout: col = lane&15, row = quad*4 + reg [m89-verified]
    long mbase = (long)blockIdx.x * 64 + wave * 16 + quad * 4;
#pragma unroll
    for (int t = 0; t < NT; ++t) {
        float b = bias[t * 16 + r16];
#pragma unroll
        for (int rr = 0; rr < 4; ++rr) {
            long mm = mbase + rr;
            if (mm < NN) {
                float v = acc[t][rr] + b;
                if (ELU) v = eluf(v);
                out[mm * N + t * 16 + r16] = v;
            }
        }
    }
    if (HIST) {
        for (int e = blockIdx.x * 256 + tid; e < E2; e += gridDim.x * 256)
            atomicAdd(&cnt[row[e]], 1);
    }
}

// ---------------- CSR: per-chunk scan, chunk-sum scan; offsets folded into consumers
__global__ __launch_bounds__(256) void k_scan1(const int* __restrict__ cnt, int* __restrict__ start,
                                               int* __restrict__ bsum) {
    __shared__ int s[256];
    int b = blockIdx.x, t = threadIdx.x;
    int i = b * 256 + t;
    int v = (i < NN) ? cnt[i] : 0;
    s[t] = v;
    __syncthreads();
    for (int off = 1; off < 256; off <<= 1) {
        int add = (t >= off) ? s[t - off] : 0;
        __syncthreads();
        s[t] += add;
        __syncthreads();
    }
    if (i < NN) start[i] = s[t] - v;      // chunk-local exclusive
    if (t == 255) bsum[b] = s[t];
}
__global__ __launch_bounds__(256) void k_scan2(const int* __restrict__ bsum, int* __restrict__ bofs, int nb) {
    __shared__ int s[256];
    int t = threadIdx.x;
    int v = (t < nb) ? bsum[t] : 0;
    s[t] = v;
    __syncthreads();
    for (int off = 1; off < 256; off <<= 1) {
        int add = (t >= off) ? s[t - off] : 0;
        __syncthreads();
        s[t] += add;
        __syncthreads();
    }
    if (t < nb) bofs[t] = s[t] - v;
}
__global__ __launch_bounds__(256) void k_fill(const int* __restrict__ row, const int* __restrict__ start,
                                              const int* __restrict__ bofs,
                                              int* __restrict__ fill, int* __restrict__ eslot) {
    int e = blockIdx.x * 256 + threadIdx.x;
    if (e >= E2) return;
    int u = row[e];
    eslot[e] = start[u] + bofs[u >> 8] + atomicAdd(&fill[u], 1);
}

// ---------------- y (packed bf16 uint2) + node projections; zeroes deg for this layer
__global__ __launch_bounds__(256) void k_y8(const float* __restrict__ xc,
                                            const float* __restrict__ Wl, const float* __restrict__ Wr,
                                            const float* __restrict__ Wsh, const float* __restrict__ Wwt,
                                            int layer, uint2* __restrict__ yp,
                                            float* __restrict__ aR, float* __restrict__ aC,
                                            float* __restrict__ wR, float* __restrict__ wC,
                                            float* __restrict__ deg) {
    __shared__ float wrs[32 * 33];
    __shared__ float wls[9];
    __shared__ float xcs[8][96];
    __shared__ float ws1[192], wt[192];
    int tid = threadIdx.x;
    int n0 = blockIdx.x * 8;
    if (tid < 8) { int nz = n0 + tid; if (nz < NN) deg[nz] = 0.0f; }
    for (int i = tid; i < 1024; i += 256) wrs[(i >> 5) * 33 + (i & 31)] = Wr[i];
    if (tid < 9) wls[tid] = Wl[tid];
    if (tid < 192) {
        ws1[tid] = Wsh[(layer * 3 + 1) * 192 + tid];  // only row 1 of W_sheaf survives Cayley (D=2)
        wt[tid]  = Wwt[layer * 192 + tid];
    }
    for (int i = tid; i < 768; i += 256) {
        int n = n0 + i / 96;
        xcs[i / 96][i % 96] = (n < NN) ? xc[n * 96 + i % 96] : 0.0f;
    }
    __syncthreads();
    int node = tid >> 5, c = tid & 31;
    int n = n0 + node;
    float a1 = 0, a2 = 0, a3 = 0, a4 = 0;
#pragma unroll
    for (int j = 0; j < 3; ++j) {
        int k = j * 32 + c;
        float xv = xcs[node][k];
        a1 = fmaf(xv, ws1[k], a1);
        a2 = fmaf(xv, ws1[96 + k], a2);
        a3 = fmaf(xv, wt[k], a3);
        a4 = fmaf(xv, wt[96 + k], a4);
    }
#pragma unroll
    for (int off = 16; off; off >>= 1) {
        a1 += __shfl_xor(a1, off);
        a2 += __shfl_xor(a2, off);
        a3 += __shfl_xor(a3, off);
        a4 += __shfl_xor(a4, off);
    }
    if (c == 0 && n < NN) { aR[n] = a1; aC[n] = a2; wR[n] = a3; wC[n] = a4; }
    if (n < NN) {
        float t0 = 0, t1 = 0, t2 = 0;
        const float* wr = &wrs[c * 33];
        const float* xr = xcs[node];
#pragma unroll
        for (int h = 0; h < 32; ++h) {
            float w = wr[h];
            t0 = fmaf(xr[h], w, t0);
            t1 = fmaf(xr[32 + h], w, t1);
            t2 = fmaf(xr[64 + h], w, t2);
        }
        float o0 = wls[0] * t0 + wls[1] * t1 + wls[2] * t2;
        float o1 = wls[3] * t0 + wls[4] * t1 + wls[5] * t2;
        float o2 = wls[6] * t0 + wls[7] * t1 + wls[8] * t2;
        yp[n * 32 + c] = make_uint2(rne_bf16(o0) | (rne_bf16(o1) << 16), rne_bf16(o2));
    }
}

// ---------------- per-edge coefficients (E0 only; reverse via T^T symmetry) + degree
__global__ __launch_bounds__(256) void k_coef(const int* __restrict__ row, const int* __restrict__ col,
                                              const int* __restrict__ eslot,
                                              const float* __restrict__ aR, const float* __restrict__ aC,
                                              const float* __restrict__ wR, const float* __restrict__ wC,
                                              float4* __restrict__ meta, float* __restrict__ deg) {
    int e = blockIdx.x * 256 + threadIdx.x;
    if (e >= E0) return;
    int u = row[e], v = col[e];
    float a_e = tanhf(aR[u] + aC[v]);
    float a_r = tanhf(aR[v] + aC[u]);
    float wd_e = sigmoidf(wR[u] + wC[v]);
    float wd_r = sigmoidf(wR[v] + wC[u]);
    float w = wd_e * wd_r;
    float w2 = w * w;
    float ie = 1.0f / (1.0f + a_e * a_e), ir = 1.0f / (1.0f + a_r * a_r);
    float ce = (1.0f - a_e * a_e) * ie, se = 2.0f * a_e * ie;
    float cr = (1.0f - a_r * a_r) * ir, sr = 2.0f * a_r * ir;
    float C = ce * cr + se * sr;   // T_e = Q_e^T Q_rev ; T_rev = T_e^T -> (C,-S)
    float S = ce * sr - se * cr;
    meta[eslot[e]]      = make_float4(C,  S, w2, __int_as_float(v));
    meta[eslot[e + E0]] = make_float4(C, -S, w2, __int_as_float(u));
    atomicAdd(&deg[u], w2);
    atomicAdd(&deg[v], w2);
}

__global__ __launch_bounds__(256) void k_dinv(const float* __restrict__ deg, float* __restrict__ dinv) {
    int n = blockIdx.x * 256 + threadIdx.x;
    if (n >= NN) return;
    float d = deg[n];
    dinv[n] = d > 0.0f ? rsqrtf(fmaxf(d, 1e-30f)) : 0.0f;
}

// ---------------- gather + residual update (8B packed y, slot-ordered meta, shfl broadcast)
__global__ __launch_bounds__(256) void k_gather(const int* __restrict__ start, const int* __restrict__ bofs,
                                                const int* __restrict__ cnt,
                                                const float4* __restrict__ meta,
                                                const float* __restrict__ dinv,
                                                const uint2* __restrict__ yp,
                                                const float* __restrict__ eps,
                                                int layer, float* __restrict__ xc) {
    int tid = threadIdx.x;
    int node = tid >> 5, c = tid & 31;
    int n = blockIdx.x * 8 + node;
    if (n >= NN) return;
    int s0 = start[n] + bofs[n >> 8], ec = cnt[n];
    float du = dinv[n];
    float acc0 = 0, acc1 = 0, acc2 = 0;
    for (int bs = 0; bs < ec; bs += 32) {
        int nb2 = min(32, ec - bs);
        float CC = 0, SS = 0, cnl = 0;
        int vj = 0;
        if (c < nb2) {
            float4 mt = meta[s0 + bs + c];
            vj = __float_as_int(mt.w);
            cnl = mt.z * du * dinv[vj];
            CC = cnl * mt.x;
            SS = cnl * mt.y;
        }
        for (int j = 0; j < nb2; ++j) {
            float Cj = __shfl(CC, j, 32);
            float Sj = __shfl(SS, j, 32);
            float cj = __shfl(cnl, j, 32);
            int v = __shfl(vj, j, 32);
            uint2 uy = yp[v * 32 + c];
            float y0 = __uint_as_float(uy.x << 16);
            float y1 = __uint_as_float(uy.x & 0xffff0000u);
            float y2 = __uint_as_float(uy.y << 16);
            acc0 = fmaf(Cj, y0, acc0);
            acc0 = fmaf(-Sj, y1, acc0);
            acc1 = fmaf(Sj, y0, acc1);
            acc1 = fmaf(Cj, y1, acc1);
            acc2 = fmaf(cj, y2, acc2);
        }
    }
    float diag = du > 0.0f ? 1.0f : 0.0f;
    uint2 uy = yp[n * 32 + c];
    float oy0 = __uint_as_float(uy.x << 16);
    float oy1 = __uint_as_float(uy.x & 0xffff0000u);
    float oy2 = __uint_as_float(uy.y << 16);
    float c0 = 1.0f + tanhf(eps[layer * 3 + 0]);
    float c1 = 1.0f + tanhf(eps[layer * 3 + 1]);
    float c2 = 1.0f + tanhf(eps[layer * 3 + 2]);
    int base = n * 96 + c;
    float z0 = eluf(diag * oy0 - acc0);
    float z1 = eluf(diag * oy1 - acc1);
    float z2 = eluf(diag * oy2 - acc2);
    xc[base]      = c0 * xc[base]      - z0;
    xc[base + 32] = c1 * xc[base + 32] - z1;
    xc[base + 64] = c2 * xc[base + 64] - z2;
}

extern "C" void kernel_launch(void* const* d_in, const int* in_sizes, int n_in,
                              void* d_out, int out_size, void* d_ws, size_t ws_size,
                              hipStream_t stream) {
    const float* x     = (const float*)d_in[0];
    const int*   ei    = (const int*)d_in[1];
    const float* W1    = (const float*)d_in[2];
    const float* b1    = (const float*)d_in[3];
    const float* W2    = (const float*)d_in[4];
    const float* b2    = (const float*)d_in[5];
    const float* Wl    = (const float*)d_in[6];
    const float* Wr    = (const float*)d_in[7];
    const float* eps   = (const float*)d_in[8];
    const float* Wsh   = (const float*)d_in[9];
    const float* Wwt   = (const float*)d_in[10];
    float* out = (float*)d_out;
    const int* row = ei;        // edge_index[0]
    const int* col = ei + E2;   // edge_index[1]

    char* pc = (char*)d_ws;
    float* xc    = (float*)pc;          pc += (size_t)NN * 96 * 4;
    float4* meta = (float4*)pc;         pc += (size_t)E2 * 16;
    uint2* yp    = (uint2*)pc;          pc += (size_t)NN * 32 * 8;
    float* aR    = (float*)pc;          pc += (size_t)NN * 4;
    float* aC    = (float*)pc;          pc += (size_t)NN * 4;
    float* wRp   = (float*)pc;          pc += (size_t)NN * 4;
    float* wCp   = (float*)pc;          pc += (size_t)NN * 4;
    float* deg   = (float*)pc;          pc += (size_t)NN * 4;
    float* dinv  = (float*)pc;          pc += (size_t)NN * 4;
    float* Wl_n  = (float*)pc;          pc += 32 * 4;
    float* Wr_n  = (float*)pc;          pc += 2048 * 4;
    int* cnt     = (int*)pc;            pc += (size_t)NN * 4;
    int* start   = (int*)pc;            pc += (size_t)NN * 4;
    int* fill    = (int*)pc;            pc += (size_t)NN * 4;
    int* eslot   = (int*)pc;            pc += (size_t)E2 * 4;
    int* bsum    = (int*)pc;            pc += 256 * 4;
    int* bofs    = (int*)pc;            pc += 256 * 4;
    unsigned short* w1hi = (unsigned short*)pc; pc += 96 * 128 * 2;
    unsigned short* w1lo = (unsigned short*)pc; pc += 96 * 128 * 2;
    unsigned short* w2hi = (unsigned short*)pc; pc += 32 * 96 * 2;
    unsigned short* w2lo = (unsigned short*)pc; pc += 32 * 96 * 2;

    const int EB = (E2 + 255) / 256;

    // 14 dispatches total
    k_setup<<<66, 256, 0, stream>>>(W1, W2, Wl, Wr, Wl_n, Wr_n,
                                    w1hi, w1lo, w2hi, w2lo, cnt, fill, deg);
    k_gemm<128, 96, true, true><<<NTILES, 256, 0, stream>>>(x, w1hi, w1lo, b1, xc, row, cnt);
    k_scan1<<<NCHUNK, 256, 0, stream>>>(cnt, start, bsum);
    k_scan2<<<1, 256, 0, stream>>>(bsum, bofs, NCHUNK);
    k_fill<<<EB, 256, 0, stream>>>(row, start, bofs, fill, eslot);
    for (int l = 0; l < 2; ++l) {
        k_y8<<<NGROUPS, 256, 0, stream>>>(xc, Wl_n + l * 9, Wr_n + l * 1024, Wsh, Wwt, l,
                                          yp, aR, aC, wRp, wCp, deg);
        k_coef<<<(E0 + 255) / 256, 256, 0, stream>>>(row, col, eslot, aR, aC, wRp, wCp, meta, deg);
        k_dinv<<<NCHUNK, 256, 0, stream>>>(deg, dinv);
        k_gather<<<NGROUPS, 256, 0, stream>>>(start, bofs, cnt, meta, dinv, yp, eps, l, xc);
    }
    k_gemm<96, 32, false, false><<<NTILES, 256, 0, stream>>>(xc, w2hi, w2lo, b2, out, nullptr, nullptr);
}

// Round 10
// 361.138 us; speedup vs baseline: 1.0173x; 1.0173x over previous
//
#include <hip/hip_runtime.h>

#define NN 50000
#define E0 200000
#define E2 400000
#define NGROUPS ((NN + 7) / 8)      // 6250
#define NCHUNK  ((NN + 255) / 256)  // 196
#define NTILES  ((NN + 63) / 64)    // 782

typedef __attribute__((ext_vector_type(8))) short short8;
typedef __attribute__((ext_vector_type(4))) float f32x4;

__device__ __forceinline__ float eluf(float x) { return x > 0.0f ? x : expm1f(x); }
__device__ __forceinline__ float sigmoidf(float x) { return 1.0f / (1.0f + expf(-x)); }
__device__ __forceinline__ unsigned rne_bf16(float x) {
    unsigned u = __float_as_uint(x);
    return (u + 0x7fffu + ((u >> 16) & 1u)) >> 16;
}

// ---------------- setup: spectral norm + zero cnt/fill/deg (1 dispatch)
__global__ __launch_bounds__(256) void k_setup(const float* __restrict__ Wl_in, const float* __restrict__ Wr_in,
                                               float* __restrict__ Wl_out, float* __restrict__ Wr_out,
                                               int* __restrict__ cnt, int* __restrict__ fill,
                                               float* __restrict__ deg) {
    __shared__ float W[32 * 33];
    __shared__ float us[32], vs[32], tmp[32];
    __shared__ float scal;
    int t = threadIdx.x;
    if (blockIdx.x < 2) {
        int l = blockIdx.x;
        for (int i = t; i < 1024; i += 256) W[(i >> 5) * 33 + (i & 31)] = Wr_in[l * 1024 + i];
        if (t < 32) us[t] = 0.17677669529663688f;
        __syncthreads();
        for (int it = 0; it < 20; ++it) {
            if (t < 32) { float a = 0; for (int r = 0; r < 32; ++r) a = fmaf(W[r * 33 + t], us[r], a); tmp[t] = a; }
            __syncthreads();
            if (t == 0) { float s = 0; for (int c = 0; c < 32; ++c) s += tmp[c] * tmp[c]; scal = 1.0f / (sqrtf(s) + 1e-12f); }
            __syncthreads();
            if (t < 32) vs[t] = tmp[t] * scal;
            __syncthreads();
            if (t < 32) { float a = 0; for (int c = 0; c < 32; ++c) a = fmaf(W[t * 33 + c], vs[c], a); tmp[t] = a; }
            __syncthreads();
            if (t == 0) { float s = 0; for (int r = 0; r < 32; ++r) s += tmp[r] * tmp[r]; scal = 1.0f / (sqrtf(s) + 1e-12f); }
            __syncthreads();
            if (t < 32) us[t] = tmp[t] * scal;
            __syncthreads();
        }
        if (t < 32) { float a = 0; for (int r = 0; r < 32; ++r) a = fmaf(W[r * 33 + t], us[r], a); tmp[t] = a; }
        __syncthreads();
        if (t == 0) {
            float s = 0; for (int c = 0; c < 32; ++c) s += tmp[c] * tmp[c];
            scal = (sqrtf(s) + 1e-12f) / s;   // 1/sigma
        }
        __syncthreads();
        for (int i = t; i < 1024; i += 256) Wr_out[l * 1024 + i] = W[(i >> 5) * 33 + (i & 31)] * scal;
        if (t == 0) {
            float M[9];
            for (int i = 0; i < 9; ++i) M[i] = Wl_in[l * 9 + i];
            float u[3] = {0.5773502691896258f, 0.5773502691896258f, 0.5773502691896258f};
            float v[3], u2[3];
            for (int it = 0; it < 20; ++it) {
                float s = 0;
                for (int c = 0; c < 3; ++c) { v[c] = M[c] * u[0] + M[3 + c] * u[1] + M[6 + c] * u[2]; s += v[c] * v[c]; }
                float inv = 1.0f / (sqrtf(s) + 1e-12f);
                for (int c = 0; c < 3; ++c) v[c] *= inv;
                s = 0;
                for (int r = 0; r < 3; ++r) { u2[r] = M[r * 3] * v[0] + M[r * 3 + 1] * v[1] + M[r * 3 + 2] * v[2]; s += u2[r] * u2[r]; }
                inv = 1.0f / (sqrtf(s) + 1e-12f);
                for (int r = 0; r < 3; ++r) u[r] = u2[r] * inv;
            }
            float s = 0;
            for (int c = 0; c < 3; ++c) { v[c] = M[c] * u[0] + M[3 + c] * u[1] + M[6 + c] * u[2]; s += v[c] * v[c]; }
            float inv = (sqrtf(s) + 1e-12f) / s;
            for (int i = 0; i < 9; ++i) Wl_out[l * 9 + i] = M[i] * inv;
        }
    } else {
        int base = (blockIdx.x - 2) * 256 + t;
        int stride = (gridDim.x - 2) * 256;
        for (int i = base; i < NN; i += stride) { cnt[i] = 0; fill[i] = 0; deg[i] = 0.0f; }
    }
}

// ---------------- MFMA GEMM, LDS-staged W (converted f32->bf16 hi/lo in-flight):
// out[M,N] = act(X[M,K] @ W[N,K]^T + b), split-bf16 (3 MFMA products).
// Optional histogram tail issued FIRST so its atomics hide behind staging+MFMA.
template<int K, int N, bool ELU, bool HIST>
__global__ __launch_bounds__(256) void k_gemm(const float* __restrict__ X,
                                              const float* __restrict__ W,
                                              const float* __restrict__ bias,
                                              float* __restrict__ out,
                                              const int* __restrict__ row, int* __restrict__ cnt) {
    constexpr int KP = K + 8;
    constexpr int NT = N / 16;
    constexpr int KS = K / 32;
    __shared__ __align__(16) unsigned short whi[N * KP];
    __shared__ __align__(16) unsigned short wlo[N * KP];
    int tid = threadIdx.x;
    if (HIST) {   // fire-and-forget atomics; latency overlaps the GEMM below
        for (int e = blockIdx.x * 256 + tid; e < E2; e += gridDim.x * 256)
            atomicAdd(&cnt[row[e]], 1);
    }
    for (int i = tid; i < N * K; i += 256) {     // coalesced f32 read + in-register split
        float v = W[i];
        int r = i / K, c = i % K;
        unsigned h = rne_bf16(v);
        whi[r * KP + c] = (unsigned short)h;
        wlo[r * KP + c] = (unsigned short)rne_bf16(v - __uint_as_float(h << 16));
    }
    __syncthreads();
    int wave = tid >> 6, lane = tid & 63;
    int quad = lane >> 4, r16 = lane & 15;
    long m = (long)blockIdx.x * 64 + wave * 16 + r16;
    long mc = m < NN ? m : (NN - 1);      // clamp OOB A-loads; stores guarded
    const float* xrow = X + mc * K + quad * 8;
    short8 ah[KS], al[KS];
#pragma unroll
    for (int ks = 0; ks < KS; ++ks) {
        const float4* xp = (const float4*)(xrow + ks * 32);
        float4 p0 = xp[0], p1 = xp[1];
        float xv[8] = {p0.x, p0.y, p0.z, p0.w, p1.x, p1.y, p1.z, p1.w};
#pragma unroll
        for (int j = 0; j < 8; ++j) {
            unsigned h = rne_bf16(xv[j]);
            ah[ks][j] = (short)h;
            al[ks][j] = (short)rne_bf16(xv[j] - __uint_as_float(h << 16));
        }
    }
    long mbase = (long)blockIdx.x * 64 + wave * 16 + quad * 4;
#pragma unroll
    for (int t = 0; t < NT; ++t) {
        f32x4 acc = (f32x4){0.f, 0.f, 0.f, 0.f};
#pragma unroll
        for (int ks = 0; ks < KS; ++ks) {
            int ro = (t * 16 + r16) * KP + ks * 32 + quad * 8;
            short8 bh = *(const short8*)&whi[ro];
            short8 bl = *(const short8*)&wlo[ro];
            acc = __builtin_amdgcn_mfma_f32_16x16x32_bf16(ah[ks], bh, acc, 0, 0, 0);
            acc = __builtin_amdgcn_mfma_f32_16x16x32_bf16(al[ks], bh, acc, 0, 0, 0);
            acc = __builtin_amdgcn_mfma_f32_16x16x32_bf16(ah[ks], bl, acc, 0, 0, 0);
        }
        // C/D layout: col = lane&15, row = quad*4 + reg [m89-verified]
        float b = bias[t * 16 + r16];
#pragma unroll
        for (int rr = 0; rr < 4; ++rr) {
            long mm = mbase + rr;
            if (mm < NN) {
                float v = acc[rr] + b;
                if (ELU) v = eluf(v);
                out[mm * N + t * 16 + r16] = v;
            }
        }
    }
}

// ---------------- CSR: per-chunk scan, chunk-sum scan; offsets folded into consumers
__global__ __launch_bounds__(256) void k_scan1(const int* __restrict__ cnt, int* __restrict__ start,
                                               int* __restrict__ bsum) {
    __shared__ int s[256];
    int b = blockIdx.x, t = threadIdx.x;
    int i = b * 256 + t;
    int v = (i < NN) ? cnt[i] : 0;
    s[t] = v;
    __syncthreads();
    for (int off = 1; off < 256; off <<= 1) {
        int add = (t >= off) ? s[t - off] : 0;
        __syncthreads();
        s[t] += add;
        __syncthreads();
    }
    if (i < NN) start[i] = s[t] - v;      // chunk-local exclusive
    if (t == 255) bsum[b] = s[t];
}
__global__ __launch_bounds__(256) void k_scan2(const int* __restrict__ bsum, int* __restrict__ bofs, int nb) {
    __shared__ int s[256];
    int t = threadIdx.x;
    int v = (t < nb) ? bsum[t] : 0;
    s[t] = v;
    __syncthreads();
    for (int off = 1; off < 256; off <<= 1) {
        int add = (t >= off) ? s[t - off] : 0;
        __syncthreads();
        s[t] += add;
        __syncthreads();
    }
    if (t < nb) bofs[t] = s[t] - v;
}
__global__ __launch_bounds__(256) void k_fill(const int* __restrict__ row, const int* __restrict__ start,
                                              const int* __restrict__ bofs,
                                              int* __restrict__ fill, int* __restrict__ eslot) {
    int e = blockIdx.x * 256 + threadIdx.x;
    if (e >= E2) return;
    int u = row[e];
    eslot[e] = start[u] + bofs[u >> 8] + atomicAdd(&fill[u], 1);
}

// ---------------- y (packed bf16 uint2) + node projections; zeroes deg for this layer
__global__ __launch_bounds__(256) void k_y8(const float* __restrict__ xc,
                                            const float* __restrict__ Wl, const float* __restrict__ Wr,
                                            const float* __restrict__ Wsh, const float* __restrict__ Wwt,
                                            int layer, uint2* __restrict__ yp,
                                            float* __restrict__ aR, float* __restrict__ aC,
                                            float* __restrict__ wR, float* __restrict__ wC,
                                            float* __restrict__ deg) {
    __shared__ float wrs[32 * 33];
    __shared__ float wls[9];
    __shared__ float xcs[8][96];
    __shared__ float ws1[192], wt[192];
    int tid = threadIdx.x;
    int n0 = blockIdx.x * 8;
    if (tid < 8) { int nz = n0 + tid; if (nz < NN) deg[nz] = 0.0f; }
    for (int i = tid; i < 1024; i += 256) wrs[(i >> 5) * 33 + (i & 31)] = Wr[i];
    if (tid < 9) wls[tid] = Wl[tid];
    if (tid < 192) {
        ws1[tid] = Wsh[(layer * 3 + 1) * 192 + tid];  // only row 1 of W_sheaf survives Cayley (D=2)
        wt[tid]  = Wwt[layer * 192 + tid];
    }
    for (int i = tid; i < 768; i += 256) {
        int n = n0 + i / 96;
        xcs[i / 96][i % 96] = (n < NN) ? xc[n * 96 + i % 96] : 0.0f;
    }
    __syncthreads();
    int node = tid >> 5, c = tid & 31;
    int n = n0 + node;
    float a1 = 0, a2 = 0, a3 = 0, a4 = 0;
#pragma unroll
    for (int j = 0; j < 3; ++j) {
        int k = j * 32 + c;
        float xv = xcs[node][k];
        a1 = fmaf(xv, ws1[k], a1);
        a2 = fmaf(xv, ws1[96 + k], a2);
        a3 = fmaf(xv, wt[k], a3);
        a4 = fmaf(xv, wt[96 + k], a4);
    }
#pragma unroll
    for (int off = 16; off; off >>= 1) {
        a1 += __shfl_xor(a1, off);
        a2 += __shfl_xor(a2, off);
        a3 += __shfl_xor(a3, off);
        a4 += __shfl_xor(a4, off);
    }
    if (c == 0 && n < NN) { aR[n] = a1; aC[n] = a2; wR[n] = a3; wC[n] = a4; }
    if (n < NN) {
        float t0 = 0, t1 = 0, t2 = 0;
        const float* wr = &wrs[c * 33];
        const float* xr = xcs[node];
#pragma unroll
        for (int h = 0; h < 32; ++h) {
            float w = wr[h];
            t0 = fmaf(xr[h], w, t0);
            t1 = fmaf(xr[32 + h], w, t1);
            t2 = fmaf(xr[64 + h], w, t2);
        }
        float o0 = wls[0] * t0 + wls[1] * t1 + wls[2] * t2;
        float o1 = wls[3] * t0 + wls[4] * t1 + wls[5] * t2;
        float o2 = wls[6] * t0 + wls[7] * t1 + wls[8] * t2;
        yp[n * 32 + c] = make_uint2(rne_bf16(o0) | (rne_bf16(o1) << 16), rne_bf16(o2));
    }
}

// ---------------- per-edge coefficients (E0 only; reverse via T^T symmetry) + degree
__global__ __launch_bounds__(256) void k_coef(const int* __restrict__ row, const int* __restrict__ col,
                                              const int* __restrict__ eslot,
                                              const float* __restrict__ aR, const float* __restrict__ aC,
                                              const float* __restrict__ wR, const float* __restrict__ wC,
                                              float4* __restrict__ meta, float* __restrict__ deg) {
    int e = blockIdx.x * 256 + threadIdx.x;
    if (e >= E0) return;
    int u = row[e], v = col[e];
    float a_e = tanhf(aR[u] + aC[v]);
    float a_r = tanhf(aR[v] + aC[u]);
    float wd_e = sigmoidf(wR[u] + wC[v]);
    float wd_r = sigmoidf(wR[v] + wC[u]);
    float w = wd_e * wd_r;
    float w2 = w * w;
    float ie = 1.0f / (1.0f + a_e * a_e), ir = 1.0f / (1.0f + a_r * a_r);
    float ce = (1.0f - a_e * a_e) * ie, se = 2.0f * a_e * ie;
    float cr = (1.0f - a_r * a_r) * ir, sr = 2.0f * a_r * ir;
    float C = ce * cr + se * sr;   // T_e = Q_e^T Q_rev ; T_rev = T_e^T -> (C,-S)
    float S = ce * sr - se * cr;
    meta[eslot[e]]      = make_float4(C,  S, w2, __int_as_float(v));
    meta[eslot[e + E0]] = make_float4(C, -S, w2, __int_as_float(u));
    atomicAdd(&deg[u], w2);
    atomicAdd(&deg[v], w2);
}

// ---------------- gather + residual update (deg read + inline rsqrt; no dinv pass)
__global__ __launch_bounds__(256) void k_gather(const int* __restrict__ start, const int* __restrict__ bofs,
                                                const int* __restrict__ cnt,
                                                const float4* __restrict__ meta,
                                                const float* __restrict__ deg,
                                                const uint2* __restrict__ yp,
                                                const float* __restrict__ eps,
                                                int layer, float* __restrict__ xc) {
    int tid = threadIdx.x;
    int node = tid >> 5, c = tid & 31;
    int n = blockIdx.x * 8 + node;
    if (n >= NN) return;
    int s0 = start[n] + bofs[n >> 8], ec = cnt[n];
    float dn = deg[n];
    float du = dn > 0.0f ? rsqrtf(fmaxf(dn, 1e-30f)) : 0.0f;
    float acc0 = 0, acc1 = 0, acc2 = 0;
    for (int bs = 0; bs < ec; bs += 32) {
        int nb2 = min(32, ec - bs);
        float CC = 0, SS = 0, cnl = 0;
        int vj = 0;
        if (c < nb2) {
            float4 mt = meta[s0 + bs + c];
            vj = __float_as_int(mt.w);
            float dv = deg[vj];
            float dvi = dv > 0.0f ? rsqrtf(fmaxf(dv, 1e-30f)) : 0.0f;
            cnl = mt.z * du * dvi;
            CC = cnl * mt.x;
            SS = cnl * mt.y;
        }
        for (int j = 0; j < nb2; ++j) {
            float Cj = __shfl(CC, j, 32);
            float Sj = __shfl(SS, j, 32);
            float cj = __shfl(cnl, j, 32);
            int v = __shfl(vj, j, 32);
            uint2 uy = yp[v * 32 + c];
            float y0 = __uint_as_float(uy.x << 16);
            float y1 = __uint_as_float(uy.x & 0xffff0000u);
            float y2 = __uint_as_float(uy.y << 16);
            acc0 = fmaf(Cj, y0, acc0);
            acc0 = fmaf(-Sj, y1, acc0);
            acc1 = fmaf(Sj, y0, acc1);
            acc1 = fmaf(Cj, y1, acc1);
            acc2 = fmaf(cj, y2, acc2);
        }
    }
    float diag = dn > 0.0f ? 1.0f : 0.0f;
    uint2 uy = yp[n * 32 + c];
    float oy0 = __uint_as_float(uy.x << 16);
    float oy1 = __uint_as_float(uy.x & 0xffff0000u);
    float oy2 = __uint_as_float(uy.y << 16);
    float c0 = 1.0f + tanhf(eps[layer * 3 + 0]);
    float c1 = 1.0f + tanhf(eps[layer * 3 + 1]);
    float c2 = 1.0f + tanhf(eps[layer * 3 + 2]);
    int base = n * 96 + c;
    float z0 = eluf(diag * oy0 - acc0);
    float z1 = eluf(diag * oy1 - acc1);
    float z2 = eluf(diag * oy2 - acc2);
    xc[base]      = c0 * xc[base]      - z0;
    xc[base + 32] = c1 * xc[base + 32] - z1;
    xc[base + 64] = c2 * xc[base + 64] - z2;
}

extern "C" void kernel_launch(void* const* d_in, const int* in_sizes, int n_in,
                              void* d_out, int out_size, void* d_ws, size_t ws_size,
                              hipStream_t stream) {
    const float* x     = (const float*)d_in[0];
    const int*   ei    = (const int*)d_in[1];
    const float* W1    = (const float*)d_in[2];
    const float* b1    = (const float*)d_in[3];
    const float* W2    = (const float*)d_in[4];
    const float* b2    = (const float*)d_in[5];
    const float* Wl    = (const float*)d_in[6];
    const float* Wr    = (const float*)d_in[7];
    const float* eps   = (const float*)d_in[8];
    const float* Wsh   = (const float*)d_in[9];
    const float* Wwt   = (const float*)d_in[10];
    float* out = (float*)d_out;
    const int* row = ei;        // edge_index[0]
    const int* col = ei + E2;   // edge_index[1]

    char* pc = (char*)d_ws;
    float* xc    = (float*)pc;          pc += (size_t)NN * 96 * 4;
    float4* meta = (float4*)pc;         pc += (size_t)E2 * 16;
    uint2* yp    = (uint2*)pc;          pc += (size_t)NN * 32 * 8;
    float* aR    = (float*)pc;          pc += (size_t)NN * 4;
    float* aC    = (float*)pc;          pc += (size_t)NN * 4;
    float* wRp   = (float*)pc;          pc += (size_t)NN * 4;
    float* wCp   = (float*)pc;          pc += (size_t)NN * 4;
    float* deg   = (float*)pc;          pc += (size_t)NN * 4;
    float* Wl_n  = (float*)pc;          pc += 32 * 4;
    float* Wr_n  = (float*)pc;          pc += 2048 * 4;
    int* cnt     = (int*)pc;            pc += (size_t)NN * 4;
    int* start   = (int*)pc;            pc += (size_t)NN * 4;
    int* fill    = (int*)pc;            pc += (size_t)NN * 4;
    int* eslot   = (int*)pc;            pc += (size_t)E2 * 4;
    int* bsum    = (int*)pc;            pc += 256 * 4;
    int* bofs    = (int*)pc;            pc += 256 * 4;

    const int EB = (E2 + 255) / 256;

    // 12 dispatches total
    k_setup<<<34, 256, 0, stream>>>(Wl, Wr, Wl_n, Wr_n, cnt, fill, deg);
    k_gemm<128, 96, true, true><<<NTILES, 256, 0, stream>>>(x, W1, b1, xc, row, cnt);
    k_scan1<<<NCHUNK, 256, 0, stream>>>(cnt, start, bsum);
    k_scan2<<<1, 256, 0, stream>>>(bsum, bofs, NCHUNK);
    k_fill<<<EB, 256, 0, stream>>>(row, start, bofs, fill, eslot);
    for (int l = 0; l < 2; ++l) {
        k_y8<<<NGROUPS, 256, 0, stream>>>(xc, Wl_n + l * 9, Wr_n + l * 1024, Wsh, Wwt, l,
                                          yp, aR, aC, wRp, wCp, deg);
        k_coef<<<(E0 + 255) / 256, 256, 0, stream>>>(row, col, eslot, aR, aC, wRp, wCp, meta, deg);
        k_gather<<<NGROUPS, 256, 0, stream>>>(start, bofs, cnt, meta, deg, yp, eps, l, xc);
    }
    k_gemm<96, 32, false, false><<<NTILES, 256, 0, stream>>>(xc, W2, b2, out, nullptr, nullptr);
}

// Round 11
// 345.247 us; speedup vs baseline: 1.0642x; 1.0460x over previous
//
#include <hip/hip_runtime.h>

#define NN 50000
#define E0 200000
#define E2 400000
#define NGROUPS ((NN + 7) / 8)      // 6250
#define NCHUNK  ((NN + 255) / 256)  // 196
#define NTILES  ((NN + 63) / 64)    // 782

typedef __attribute__((ext_vector_type(8))) short short8;
typedef __attribute__((ext_vector_type(4))) float f32x4;

__device__ __forceinline__ float eluf(float x) { return x > 0.0f ? x : expm1f(x); }
__device__ __forceinline__ float sigmoidf(float x) { return 1.0f / (1.0f + expf(-x)); }
__device__ __forceinline__ unsigned rne_bf16(float x) {
    unsigned u = __float_as_uint(x);
    return (u + 0x7fffu + ((u >> 16) & 1u)) >> 16;
}

// ---------------- setup: spectral norm + zero cnt/fill/deg (1 dispatch)
__global__ __launch_bounds__(256) void k_setup(const float* __restrict__ Wl_in, const float* __restrict__ Wr_in,
                                               float* __restrict__ Wl_out, float* __restrict__ Wr_out,
                                               int* __restrict__ cnt, int* __restrict__ fill,
                                               float* __restrict__ deg) {
    __shared__ float W[32 * 33];
    __shared__ float us[32], vs[32], tmp[32];
    __shared__ float scal;
    int t = threadIdx.x;
    if (blockIdx.x < 2) {
        int l = blockIdx.x;
        for (int i = t; i < 1024; i += 256) W[(i >> 5) * 33 + (i & 31)] = Wr_in[l * 1024 + i];
        if (t < 32) us[t] = 0.17677669529663688f;
        __syncthreads();
        for (int it = 0; it < 20; ++it) {
            if (t < 32) { float a = 0; for (int r = 0; r < 32; ++r) a = fmaf(W[r * 33 + t], us[r], a); tmp[t] = a; }
            __syncthreads();
            if (t == 0) { float s = 0; for (int c = 0; c < 32; ++c) s += tmp[c] * tmp[c]; scal = 1.0f / (sqrtf(s) + 1e-12f); }
            __syncthreads();
            if (t < 32) vs[t] = tmp[t] * scal;
            __syncthreads();
            if (t < 32) { float a = 0; for (int c = 0; c < 32; ++c) a = fmaf(W[t * 33 + c], vs[c], a); tmp[t] = a; }
            __syncthreads();
            if (t == 0) { float s = 0; for (int r = 0; r < 32; ++r) s += tmp[r] * tmp[r]; scal = 1.0f / (sqrtf(s) + 1e-12f); }
            __syncthreads();
            if (t < 32) us[t] = tmp[t] * scal;
            __syncthreads();
        }
        if (t < 32) { float a = 0; for (int r = 0; r < 32; ++r) a = fmaf(W[r * 33 + t], us[r], a); tmp[t] = a; }
        __syncthreads();
        if (t == 0) {
            float s = 0; for (int c = 0; c < 32; ++c) s += tmp[c] * tmp[c];
            scal = (sqrtf(s) + 1e-12f) / s;   // 1/sigma
        }
        __syncthreads();
        for (int i = t; i < 1024; i += 256) Wr_out[l * 1024 + i] = W[(i >> 5) * 33 + (i & 31)] * scal;
        if (t == 0) {
            float M[9];
            for (int i = 0; i < 9; ++i) M[i] = Wl_in[l * 9 + i];
            float u[3] = {0.5773502691896258f, 0.5773502691896258f, 0.5773502691896258f};
            float v[3], u2[3];
            for (int it = 0; it < 20; ++it) {
                float s = 0;
                for (int c = 0; c < 3; ++c) { v[c] = M[c] * u[0] + M[3 + c] * u[1] + M[6 + c] * u[2]; s += v[c] * v[c]; }
                float inv = 1.0f / (sqrtf(s) + 1e-12f);
                for (int c = 0; c < 3; ++c) v[c] *= inv;
                s = 0;
                for (int r = 0; r < 3; ++r) { u2[r] = M[r * 3] * v[0] + M[r * 3 + 1] * v[1] + M[r * 3 + 2] * v[2]; s += u2[r] * u2[r]; }
                inv = 1.0f / (sqrtf(s) + 1e-12f);
                for (int r = 0; r < 3; ++r) u[r] = u2[r] * inv;
            }
            float s = 0;
            for (int c = 0; c < 3; ++c) { v[c] = M[c] * u[0] + M[3 + c] * u[1] + M[6 + c] * u[2]; s += v[c] * v[c]; }
            float inv = (sqrtf(s) + 1e-12f) / s;
            for (int i = 0; i < 9; ++i) Wl_out[l * 9 + i] = M[i] * inv;
        }
    } else {
        int base = (blockIdx.x - 2) * 256 + t;
        int stride = (gridDim.x - 2) * 256;
        for (int i = base; i < NN; i += stride) { cnt[i] = 0; fill[i] = 0; deg[i] = 0.0f; }
    }
}

// ---------------- MFMA GEMM: multi-tile grid-stride + N column-split.
// Each block stages its NH-column slice of W ONCE (f32->bf16 hi/lo) then loops
// row-tiles barrier-free. out[M,N] = act(X[M,K] @ W[N,K]^T + b), split-bf16.
template<int K, int N, int NH, bool ELU, bool HIST>
__global__ __launch_bounds__(256) void k_gemm(const float* __restrict__ X,
                                              const float* __restrict__ W,
                                              const float* __restrict__ bias,
                                              float* __restrict__ out,
                                              const int* __restrict__ row, int* __restrict__ cnt) {
    constexpr int KP = K + 8;
    constexpr int NT = NH / 16;
    constexpr int KS = K / 32;
    constexpr int NHALVES = N / NH;
    __shared__ __align__(16) unsigned short whi[NH * KP];
    __shared__ __align__(16) unsigned short wlo[NH * KP];
    int tid = threadIdx.x;
    if (HIST) {   // independent atomics issued first; latency hides behind GEMM
        for (int e = blockIdx.x * 256 + tid; e < E2; e += gridDim.x * 256)
            atomicAdd(&cnt[row[e]], 1);
    }
    const int ch = blockIdx.x % NHALVES;          // column half
    const int tstream = blockIdx.x / NHALVES;     // tile stream
    const int nstreams = gridDim.x / NHALVES;
    for (int i = tid; i < NH * K; i += 256) {     // stage once per block
        float v = W[ch * NH * K + i];
        int r = i / K, c = i % K;
        unsigned h = rne_bf16(v);
        whi[r * KP + c] = (unsigned short)h;
        wlo[r * KP + c] = (unsigned short)rne_bf16(v - __uint_as_float(h << 16));
    }
    __syncthreads();
    int wave = tid >> 6, lane = tid & 63;
    int quad = lane >> 4, r16 = lane & 15;
    for (int t = tstream; t < NTILES; t += nstreams) {
        long m = (long)t * 64 + wave * 16 + r16;
        long mc = m < NN ? m : (NN - 1);          // clamp OOB A-loads; stores guarded
        const float* xrow = X + mc * K + quad * 8;
        short8 ah[KS], al[KS];
#pragma unroll
        for (int ks = 0; ks < KS; ++ks) {
            const float4* xp = (const float4*)(xrow + ks * 32);
            float4 p0 = xp[0], p1 = xp[1];
            float xv[8] = {p0.x, p0.y, p0.z, p0.w, p1.x, p1.y, p1.z, p1.w};
#pragma unroll
            for (int j = 0; j < 8; ++j) {
                unsigned h = rne_bf16(xv[j]);
                ah[ks][j] = (short)h;
                al[ks][j] = (short)rne_bf16(xv[j] - __uint_as_float(h << 16));
            }
        }
        long mbase = (long)t * 64 + wave * 16 + quad * 4;
#pragma unroll
        for (int tt = 0; tt < NT; ++tt) {
            f32x4 acc = (f32x4){0.f, 0.f, 0.f, 0.f};
#pragma unroll
            for (int ks = 0; ks < KS; ++ks) {
                int ro = (tt * 16 + r16) * KP + ks * 32 + quad * 8;
                short8 bh = *(const short8*)&whi[ro];
                short8 bl = *(const short8*)&wlo[ro];
                acc = __builtin_amdgcn_mfma_f32_16x16x32_bf16(ah[ks], bh, acc, 0, 0, 0);
                acc = __builtin_amdgcn_mfma_f32_16x16x32_bf16(al[ks], bh, acc, 0, 0, 0);
                acc = __builtin_amdgcn_mfma_f32_16x16x32_bf16(ah[ks], bl, acc, 0, 0, 0);
            }
            // C/D layout: col = lane&15, row = quad*4 + reg [m89-verified]
            int coln = ch * NH + tt * 16 + r16;
            float b = bias[coln];
#pragma unroll
            for (int rr = 0; rr < 4; ++rr) {
                long mm = mbase + rr;
                if (mm < NN) {
                    float v = acc[rr] + b;
                    if (ELU) v = eluf(v);
                    out[mm * N + coln] = v;
                }
            }
        }
    }
}

// ---------------- CSR: per-chunk scan, chunk-sum scan; offsets folded into consumers
__global__ __launch_bounds__(256) void k_scan1(const int* __restrict__ cnt, int* __restrict__ start,
                                               int* __restrict__ bsum) {
    __shared__ int s[256];
    int b = blockIdx.x, t = threadIdx.x;
    int i = b * 256 + t;
    int v = (i < NN) ? cnt[i] : 0;
    s[t] = v;
    __syncthreads();
    for (int off = 1; off < 256; off <<= 1) {
        int add = (t >= off) ? s[t - off] : 0;
        __syncthreads();
        s[t] += add;
        __syncthreads();
    }
    if (i < NN) start[i] = s[t] - v;      // chunk-local exclusive
    if (t == 255) bsum[b] = s[t];
}
__global__ __launch_bounds__(256) void k_scan2(const int* __restrict__ bsum, int* __restrict__ bofs, int nb) {
    __shared__ int s[256];
    int t = threadIdx.x;
    int v = (t < nb) ? bsum[t] : 0;
    s[t] = v;
    __syncthreads();
    for (int off = 1; off < 256; off <<= 1) {
        int add = (t >= off) ? s[t - off] : 0;
        __syncthreads();
        s[t] += add;
        __syncthreads();
    }
    if (t < nb) bofs[t] = s[t] - v;
}
__global__ __launch_bounds__(256) void k_fill(const int* __restrict__ row, const int* __restrict__ start,
                                              const int* __restrict__ bofs,
                                              int* __restrict__ fill, int* __restrict__ eslot) {
    int e = blockIdx.x * 256 + threadIdx.x;
    if (e >= E2) return;
    int u = row[e];
    eslot[e] = start[u] + bofs[u >> 8] + atomicAdd(&fill[u], 1);
}

// ---------------- y (packed bf16 uint2) + node projections (packed float4); zeroes deg
__global__ __launch_bounds__(256) void k_y8(const float* __restrict__ xc,
                                            const float* __restrict__ Wl, const float* __restrict__ Wr,
                                            const float* __restrict__ Wsh, const float* __restrict__ Wwt,
                                            int layer, uint2* __restrict__ yp,
                                            float4* __restrict__ proj,
                                            float* __restrict__ deg) {
    __shared__ float wrs[32 * 33];
    __shared__ float wls[9];
    __shared__ float xcs[8][96];
    __shared__ float ws1[192], wt[192];
    int tid = threadIdx.x;
    int n0 = blockIdx.x * 8;
    if (tid < 8) { int nz = n0 + tid; if (nz < NN) deg[nz] = 0.0f; }
    for (int i = tid; i < 1024; i += 256) wrs[(i >> 5) * 33 + (i & 31)] = Wr[i];
    if (tid < 9) wls[tid] = Wl[tid];
    if (tid < 192) {
        ws1[tid] = Wsh[(layer * 3 + 1) * 192 + tid];  // only row 1 of W_sheaf survives Cayley (D=2)
        wt[tid]  = Wwt[layer * 192 + tid];
    }
    for (int i = tid; i < 768; i += 256) {
        int n = n0 + i / 96;
        xcs[i / 96][i % 96] = (n < NN) ? xc[n * 96 + i % 96] : 0.0f;
    }
    __syncthreads();
    int node = tid >> 5, c = tid & 31;
    int n = n0 + node;
    float a1 = 0, a2 = 0, a3 = 0, a4 = 0;
#pragma unroll
    for (int j = 0; j < 3; ++j) {
        int k = j * 32 + c;
        float xv = xcs[node][k];
        a1 = fmaf(xv, ws1[k], a1);
        a2 = fmaf(xv, ws1[96 + k], a2);
        a3 = fmaf(xv, wt[k], a3);
        a4 = fmaf(xv, wt[96 + k], a4);
    }
#pragma unroll
    for (int off = 16; off; off >>= 1) {
        a1 += __shfl_xor(a1, off);
        a2 += __shfl_xor(a2, off);
        a3 += __shfl_xor(a3, off);
        a4 += __shfl_xor(a4, off);
    }
    if (c == 0 && n < NN) proj[n] = make_float4(a1, a2, a3, a4);   // {aR, aC, wR, wC}
    if (n < NN) {
        float t0 = 0, t1 = 0, t2 = 0;
        const float* wr = &wrs[c * 33];
        const float* xr = xcs[node];
#pragma unroll
        for (int h = 0; h < 32; ++h) {
            float w = wr[h];
            t0 = fmaf(xr[h], w, t0);
            t1 = fmaf(xr[32 + h], w, t1);
            t2 = fmaf(xr[64 + h], w, t2);
        }
        float o0 = wls[0] * t0 + wls[1] * t1 + wls[2] * t2;
        float o1 = wls[3] * t0 + wls[4] * t1 + wls[5] * t2;
        float o2 = wls[6] * t0 + wls[7] * t1 + wls[8] * t2;
        yp[n * 32 + c] = make_uint2(rne_bf16(o0) | (rne_bf16(o1) << 16), rne_bf16(o2));
    }
}

// ---------------- per-edge coefficients (E0 only; reverse via T^T symmetry) + degree
__global__ __launch_bounds__(256) void k_coef(const int* __restrict__ row, const int* __restrict__ col,
                                              const int* __restrict__ eslot,
                                              const float4* __restrict__ proj,
                                              float4* __restrict__ meta, float* __restrict__ deg) {
    int e = blockIdx.x * 256 + threadIdx.x;
    if (e >= E0) return;
    int u = row[e], v = col[e];
    float4 pu = proj[u], pv = proj[v];            // one 16B line per endpoint
    float a_e = tanhf(pu.x + pv.y);
    float a_r = tanhf(pv.x + pu.y);
    float wd_e = sigmoidf(pu.z + pv.w);
    float wd_r = sigmoidf(pv.z + pu.w);
    float w = wd_e * wd_r;
    float w2 = w * w;
    float ie = 1.0f / (1.0f + a_e * a_e), ir = 1.0f / (1.0f + a_r * a_r);
    float ce = (1.0f - a_e * a_e) * ie, se = 2.0f * a_e * ie;
    float cr = (1.0f - a_r * a_r) * ir, sr = 2.0f * a_r * ir;
    float C = ce * cr + se * sr;   // T_e = Q_e^T Q_rev ; T_rev = T_e^T -> (C,-S)
    float S = ce * sr - se * cr;
    meta[eslot[e]]      = make_float4(C,  S, w2, __int_as_float(v));
    meta[eslot[e + E0]] = make_float4(C, -S, w2, __int_as_float(u));
    atomicAdd(&deg[u], w2);
    atomicAdd(&deg[v], w2);
}

// ---------------- gather + residual update (deg read + inline rsqrt; no dinv pass)
__global__ __launch_bounds__(256) void k_gather(const int* __restrict__ start, const int* __restrict__ bofs,
                                                const int* __restrict__ cnt,
                                                const float4* __restrict__ meta,
                                                const float* __restrict__ deg,
                                                const uint2* __restrict__ yp,
                                                const float* __restrict__ eps,
                                                int layer, float* __restrict__ xc) {
    int tid = threadIdx.x;
    int node = tid >> 5, c = tid & 31;
    int n = blockIdx.x * 8 + node;
    if (n >= NN) return;
    int s0 = start[n] + bofs[n >> 8], ec = cnt[n];
    float dn = deg[n];
    float du = dn > 0.0f ? rsqrtf(fmaxf(dn, 1e-30f)) : 0.0f;
    float acc0 = 0, acc1 = 0, acc2 = 0;
    for (int bs = 0; bs < ec; bs += 32) {
        int nb2 = min(32, ec - bs);
        float CC = 0, SS = 0, cnl = 0;
        int vj = 0;
        if (c < nb2) {
            float4 mt = meta[s0 + bs + c];
            vj = __float_as_int(mt.w);
            float dv = deg[vj];
            float dvi = dv > 0.0f ? rsqrtf(fmaxf(dv, 1e-30f)) : 0.0f;
            cnl = mt.z * du * dvi;
            CC = cnl * mt.x;
            SS = cnl * mt.y;
        }
        for (int j = 0; j < nb2; ++j) {
            float Cj = __shfl(CC, j, 32);
            float Sj = __shfl(SS, j, 32);
            float cj = __shfl(cnl, j, 32);
            int v = __shfl(vj, j, 32);
            uint2 uy = yp[v * 32 + c];
            float y0 = __uint_as_float(uy.x << 16);
            float y1 = __uint_as_float(uy.x & 0xffff0000u);
            float y2 = __uint_as_float(uy.y << 16);
            acc0 = fmaf(Cj, y0, acc0);
            acc0 = fmaf(-Sj, y1, acc0);
            acc1 = fmaf(Sj, y0, acc1);
            acc1 = fmaf(Cj, y1, acc1);
            acc2 = fmaf(cj, y2, acc2);
        }
    }
    float diag = dn > 0.0f ? 1.0f : 0.0f;
    uint2 uy = yp[n * 32 + c];
    float oy0 = __uint_as_float(uy.x << 16);
    float oy1 = __uint_as_float(uy.x & 0xffff0000u);
    float oy2 = __uint_as_float(uy.y << 16);
    float c0 = 1.0f + tanhf(eps[layer * 3 + 0]);
    float c1 = 1.0f + tanhf(eps[layer * 3 + 1]);
    float c2 = 1.0f + tanhf(eps[layer * 3 + 2]);
    int base = n * 96 + c;
    float z0 = eluf(diag * oy0 - acc0);
    float z1 = eluf(diag * oy1 - acc1);
    float z2 = eluf(diag * oy2 - acc2);
    xc[base]      = c0 * xc[base]      - z0;
    xc[base + 32] = c1 * xc[base + 32] - z1;
    xc[base + 64] = c2 * xc[base + 64] - z2;
}

extern "C" void kernel_launch(void* const* d_in, const int* in_sizes, int n_in,
                              void* d_out, int out_size, void* d_ws, size_t ws_size,
                              hipStream_t stream) {
    const float* x     = (const float*)d_in[0];
    const int*   ei    = (const int*)d_in[1];
    const float* W1    = (const float*)d_in[2];
    const float* b1    = (const float*)d_in[3];
    const float* W2    = (const float*)d_in[4];
    const float* b2    = (const float*)d_in[5];
    const float* Wl    = (const float*)d_in[6];
    const float* Wr    = (const float*)d_in[7];
    const float* eps   = (const float*)d_in[8];
    const float* Wsh   = (const float*)d_in[9];
    const float* Wwt   = (const float*)d_in[10];
    float* out = (float*)d_out;
    const int* row = ei;        // edge_index[0]
    const int* col = ei + E2;   // edge_index[1]

    char* pc = (char*)d_ws;
    float* xc    = (float*)pc;          pc += (size_t)NN * 96 * 4;
    float4* meta = (float4*)pc;         pc += (size_t)E2 * 16;
    uint2* yp    = (uint2*)pc;          pc += (size_t)NN * 32 * 8;
    float4* proj = (float4*)pc;         pc += (size_t)NN * 16;
    float* deg   = (float*)pc;          pc += (size_t)NN * 4;
    float* Wl_n  = (float*)pc;          pc += 32 * 4;
    float* Wr_n  = (float*)pc;          pc += 2048 * 4;
    int* cnt     = (int*)pc;            pc += (size_t)NN * 4;
    int* start   = (int*)pc;            pc += (size_t)NN * 4;
    int* fill    = (int*)pc;            pc += (size_t)NN * 4;
    int* eslot   = (int*)pc;            pc += (size_t)E2 * 4;
    int* bsum    = (int*)pc;            pc += 256 * 4;
    int* bofs    = (int*)pc;            pc += 256 * 4;

    const int EB = (E2 + 255) / 256;

    // 12 dispatches total
    k_setup<<<34, 256, 0, stream>>>(Wl, Wr, Wl_n, Wr_n, cnt, fill, deg);
    k_gemm<128, 96, 48, true, true><<<512, 256, 0, stream>>>(x, W1, b1, xc, row, cnt);
    k_scan1<<<NCHUNK, 256, 0, stream>>>(cnt, start, bsum);
    k_scan2<<<1, 256, 0, stream>>>(bsum, bofs, NCHUNK);
    k_fill<<<EB, 256, 0, stream>>>(row, start, bofs, fill, eslot);
    for (int l = 0; l < 2; ++l) {
        k_y8<<<NGROUPS, 256, 0, stream>>>(xc, Wl_n + l * 9, Wr_n + l * 1024, Wsh, Wwt, l,
                                          yp, proj, deg);
        k_coef<<<(E0 + 255) / 256, 256, 0, stream>>>(row, col, eslot, proj, meta, deg);
        k_gather<<<NGROUPS, 256, 0, stream>>>(start, bofs, cnt, meta, deg, yp, eps, l, xc);
    }
    k_gemm<96, 32, 32, false, false><<<512, 256, 0, stream>>>(xc, W2, b2, out, nullptr, nullptr);
}